// Round 6
// baseline (585.839 us; speedup 1.0000x reference)
//
#include <hip/hip_runtime.h>
#include <hip/hip_bf16.h>

// Problem constants
#define B_    64
#define T_    1000
#define IN_   257
#define HID_  40
#define G3_   120
#define OUT_  257
#define M_    (B_*T_)   // 64000
#define NGI_  480
#define KP_   736       // padded KAN feature dim (720 real)
#define KP1_  288       // padded GEMM1 K (257 real)
#define NP_   272       // padded OUT_
#define AST_  264       // LDS A-tile row stride (256 + 8 pad, 16B-aligned)

// ws layout:
// gi0  64000x240 bf16 = 30,720,000
// gi1  240x64000 bf16 = 30,720,000
// feat 64000x80  f32  = 20,480,000
// Wk   272x736   bf16 =    400,384
// Wb   480x288   bf16 =    276,480
#define OFF_GI1  30720000ull
#define OFF_FEAT 61440000ull
#define OFF_WK   (OFF_FEAT + 20480000ull)
#define OFF_WB   (OFF_WK + 400384ull)

typedef __attribute__((ext_vector_type(8))) short bfx8;   // 8 bf16
typedef __attribute__((ext_vector_type(4))) short bfx4;   // 8 B
typedef __attribute__((ext_vector_type(4))) float f32x4;  // MFMA C/D / float4

__device__ __forceinline__ float sigf(float x){ return 1.0f/(1.0f + __expf(-x)); }
__device__ __forceinline__ float tanhfast(float x){ return 1.0f - 2.0f/(__expf(2.0f*x)+1.0f); }

__device__ __forceinline__ short bfbits(float v){
    __hip_bfloat16 h = __float2bfloat16(v);
    return *(short*)&h;
}
__device__ __forceinline__ float b2f(short s){
    return __uint_as_float(((unsigned)(unsigned short)s) << 16);
}

// Pack Wk[272][736] bf16
__global__ __launch_bounds__(256) void kprep(const float* __restrict__ bw,
                                             const float* __restrict__ sw,
                                             const float* __restrict__ ss,
                                             __hip_bfloat16* __restrict__ wk){
    int idx = blockIdx.x*256 + threadIdx.x;
    if (idx >= NP_*(KP_/8)) return;
    int o = idx / (KP_/8), q = idx % (KP_/8);
    bfx8 pk;
#pragma unroll
    for (int e=0;e<8;e++){
        int k = q*8 + e;
        float v = 0.0f;
        if (o < OUT_ && k < 720){
            if (k < 80) v = bw[o*80 + k];
            else { int i = (k-80)>>3, m = (k-80)&7; v = sw[(o*80+i)*8 + m] * ss[o*80+i]; }
        }
        pk[e] = bfbits(v);
    }
    *(bfx8*)((void*)&wk[(size_t)o*KP_ + q*8]) = pk;
}

// Pack Wb[480][288] bf16 from Wih_f | Wih_b
__global__ __launch_bounds__(256) void wprep(const float* __restrict__ Wf,
                                             const float* __restrict__ Wbk,
                                             __hip_bfloat16* __restrict__ wb){
    int idx = blockIdx.x*256 + threadIdx.x;
    if (idx >= NGI_*(KP1_/8)) return;
    int n = idx / (KP1_/8), q = idx % (KP1_/8);
    bfx8 pk;
#pragma unroll
    for (int e=0;e<8;e++){
        int k = q*8 + e;
        float v = 0.0f;
        if (k < IN_) v = (n < 240) ? Wf[(size_t)n*IN_ + k] : Wbk[(size_t)(n-240)*IN_ + k];
        pk[e] = bfbits(v);
    }
    *(bfx8*)((void*)&wb[(size_t)n*KP1_ + q*8]) = pk;
}

// GEMM1 (MFMA): layer0 gates -> gi0[m][240] row-major, layer1 gates -> gi1[gate][m] col-major
__global__ __launch_bounds__(256) void k1_gemm(const float* __restrict__ X,
                                               const __hip_bfloat16* __restrict__ Wb16,
                                               const float* __restrict__ bf,
                                               const float* __restrict__ bb,
                                               __hip_bfloat16* __restrict__ gi0,
                                               __hip_bfloat16* __restrict__ gi1){
    __shared__ __hip_bfloat16 Asm[128*40];
    __shared__ __hip_bfloat16 Bsm[160*40];
    int tid = threadIdx.x, wave = tid>>6, lane = tid&63;
    int m0 = blockIdx.y*128, n0 = blockIdx.x*160;
    f32x4 acc[2][10];
#pragma unroll
    for (int s=0;s<2;s++)
#pragma unroll
        for (int j=0;j<10;j++) acc[s][j] = (f32x4){0.f,0.f,0.f,0.f};

    for (int k0=0;k0<KP1_;k0+=32){
#pragma unroll
        for (int p=0;p<2;p++){
            int c = tid + p*256;
            int row = c>>2, kc = (c&3)*8;
            bfx8 pk;
#pragma unroll
            for (int e=0;e<8;e++){
                int k = k0 + kc + e;
                float v = (k < IN_) ? X[(size_t)(m0+row)*IN_ + k] : 0.0f;
                pk[e] = bfbits(v);
            }
            *(bfx8*)((void*)&Asm[row*40 + kc]) = pk;
        }
#pragma unroll
        for (int p=0;p<3;p++){
            int c = tid + p*256;
            if (c < 640){
                int row = c>>2, kc = (c&3)*8;
                *(bfx8*)((void*)&Bsm[row*40 + kc]) =
                    *(const bfx8*)&Wb16[(size_t)(n0+row)*KP1_ + k0 + kc];
            }
        }
        __syncthreads();
        int kf = (lane>>4)*8, rl = lane&15;
        bfx8 a0 = *(bfx8*)((void*)&Asm[(wave*32 + rl)*40 + kf]);
        bfx8 a1 = *(bfx8*)((void*)&Asm[(wave*32 + 16 + rl)*40 + kf]);
#pragma unroll
        for (int j=0;j<10;j++){
            bfx8 b = *(bfx8*)((void*)&Bsm[(j*16 + rl)*40 + kf]);
            acc[0][j] = __builtin_amdgcn_mfma_f32_16x16x32_bf16(a0, b, acc[0][j], 0,0,0);
            acc[1][j] = __builtin_amdgcn_mfma_f32_16x16x32_bf16(a1, b, acc[1][j], 0,0,0);
        }
        __syncthreads();
    }
    int rl = lane&15, quad = lane>>4;
#pragma unroll
    for (int j=0;j<10;j++){
        int n = n0 + j*16 + rl;
        float bias = (n < 240) ? bf[n] : bb[n-240];
        int d  = (n >= 240) ? 1 : 0;
        int nn = n - 240*d;
#pragma unroll
        for (int s=0;s<2;s++){
            int mb = m0 + wave*32 + s*16 + quad*4;
            if (nn < 120){
#pragma unroll
                for (int r=0;r<4;r++)
                    gi0[(size_t)(mb+r)*240 + d*120 + nn] = __float2bfloat16(acc[s][j][r] + bias);
            } else {
                bfx4 v;
#pragma unroll
                for (int r=0;r<4;r++) v[r] = bfbits(acc[s][j][r] + bias);
                *(bfx4*)((void*)&gi1[(size_t)(d*120 + nn - 120)*M_ + mb]) = v;
            }
        }
    }
}

// Pointwise GRU -> feat[64000][80] f32 (raw h1; fwd 0..40, bwd 40..80).
// Fully unrolled so h0[] stays register-resident (Round-5 lesson: rolled outer
// loop made h0[j] dynamic -> LDS/scratch detour, 52 VGPR, 260us).
__global__ __launch_bounds__(64, 4) void k2_gru(const __hip_bfloat16* __restrict__ gi0,
                                                const __hip_bfloat16* __restrict__ gi1,
                                                const float* __restrict__ Whh_f,
                                                const float* __restrict__ bhh_f,
                                                const float* __restrict__ Whh_b,
                                                const float* __restrict__ bhh_b,
                                                float* __restrict__ feat){
    int tid = threadIdx.x;
    int dir = (blockIdx.x >= 1000) ? 1 : 0;   // block-uniform
    int m = (blockIdx.x - dir*1000)*64 + tid;
    int b = m / T_, t = m % T_;
    int src = dir ? (b*T_ + (T_-1-t)) : m;
    const float* Whh1  = (dir ? Whh_b : Whh_f) + G3_*HID_;
    const float* bhh0v = dir ? bhh_b : bhh_f;
    const float* bhh1  = bhh0v + G3_;

    // layer 0: 15 x 16B vector loads, register-resident
    const bfx8* g0 = (const bfx8*)(gi0 + (size_t)src*240 + dir*120);
    bfx8 c[15];
#pragma unroll
    for (int q=0;q<15;q++) c[q] = g0[q];
    float h0[HID_];
#pragma unroll
    for (int j=0;j<HID_;j++){
        float ir = b2f(c[j>>3][j&7]);
        float iz = b2f(c[(40+j)>>3][(40+j)&7]);
        float in = b2f(c[(80+j)>>3][(80+j)&7]);
        float r = sigf(ir + bhh0v[j]);
        float z = sigf(iz + bhh0v[40+j]);
        float n = tanhfast(in + r*bhh0v[80+j]);
        h0[j] = (1.0f - z)*n;
    }

    const __hip_bfloat16* g1 = gi1 + (size_t)(dir*120)*M_ + src;
    float* featp = feat + (size_t)m*80 + dir*40;

    // layer 1: fully unrolled; coalesced gi1 column reads; float4 feat stores
#pragma unroll
    for (int jo=0;jo<10;jo++){
        f32x4 hv;
#pragma unroll
        for (int jj=0;jj<4;jj++){
            int j = jo*4 + jj;
            float gr = bhh1[j], gz = bhh1[40+j], gn = bhh1[80+j];
#pragma unroll
            for (int k=0;k<HID_;k++){
                float h = h0[k];
                gr += Whh1[j*HID_+k]      * h;
                gz += Whh1[(40+j)*HID_+k] * h;
                gn += Whh1[(80+j)*HID_+k] * h;
            }
            float ir = b2f(*(const short*)&g1[(size_t)j*M_]);
            float iz = b2f(*(const short*)&g1[(size_t)(40+j)*M_]);
            float in = b2f(*(const short*)&g1[(size_t)(80+j)*M_]);
            float r = sigf(ir + gr);
            float z = sigf(iz + gz);
            float n = tanhfast(in + r*gn);
            hv[jj] = (1.0f - z)*n + z*h0[j];
        }
        *(f32x4*)((void*)&featp[jo*4]) = hv;
    }
}

// Fused KAN GEMM: builds P-tile (silu + closed-form cubic B-spline) in LDS per
// 256-k section, MFMA against L2-resident Wk. P never touches HBM.
__global__ __launch_bounds__(256, 3) void k3_kan(const float* __restrict__ feat,
                                                 const __hip_bfloat16* __restrict__ Wk,
                                                 const float* __restrict__ slope,
                                                 float* __restrict__ outp){
    __shared__ __hip_bfloat16 As[64*AST_];   // 33,792 B
    int tid = threadIdx.x, wave = tid>>6, lane = tid&63;
    int rl = lane&15, quad = lane>>4;
    int m0 = blockIdx.x*64;
    const int SECK[4] = {0,256,512,736};
    const int SECJ[4] = {0,22,54,80};

    f32x4 acc[17];
#pragma unroll
    for (int j=0;j<17;j++) acc[j] = (f32x4){0.f,0.f,0.f,0.f};

    for (int s=0;s<3;s++){
        // zero A-section (incl. pad cols and k>=720 zeros)
        bfx8 z8 = {0,0,0,0,0,0,0,0};
#pragma unroll
        for (int i=0;i<9;i++){
            int cc = tid + i*256;
            if (cc < (64*AST_)/8) *(bfx8*)((void*)&As[cc*8]) = z8;
        }
        __syncthreads();
        // build
        {
            int row = tid & 63, g = tid >> 6;
            const float* frow = feat + (size_t)(m0+row)*80;
            if (s == 0){
                for (int fi = g*20; fi < g*20+20; fi++){
                    float x = frow[fi];
                    As[row*AST_ + fi] = __float2bfloat16(x * sigf(x));
                }
            }
            int cnt = SECJ[s+1] - SECJ[s];
            int jlo = SECJ[s] + ((cnt*g)>>2);
            int jhi = SECJ[s] + ((cnt*(g+1))>>2);
            for (int j = jlo; j < jhi; j++){
                float x  = frow[j];
                float xf = (x + 1.0f)*2.5f;
                int cell = (int)floorf(xf);
                cell = cell < 0 ? 0 : (cell > 4 ? 4 : cell);
                float u  = xf - (float)cell;
                float um = 1.0f - u;
                float u2 = u*u, u3 = u2*u;
                float w0 = um*um*um*(1.0f/6.0f);
                float w1 = (3.0f*u3 - 6.0f*u2 + 4.0f)*(1.0f/6.0f);
                float w2 = (-3.0f*u3 + 3.0f*u2 + 3.0f*u + 1.0f)*(1.0f/6.0f);
                float w3 = u3*(1.0f/6.0f);
                int kk = 80 + j*8 + cell - SECK[s];
                __hip_bfloat16* pa = &As[row*AST_ + kk];
                pa[0] = __float2bfloat16(w0);
                pa[1] = __float2bfloat16(w1);
                pa[2] = __float2bfloat16(w2);
                pa[3] = __float2bfloat16(w3);
            }
        }
        __syncthreads();
        // MFMA over this section
        int kiters = (s == 2) ? 7 : 8;
        for (int ki=0; ki<kiters; ki++){
            int kl = ki*32 + quad*8;
            bfx8 a = *(bfx8*)((void*)&As[(wave*16 + rl)*AST_ + kl]);
            int kg = SECK[s] + kl;
#pragma unroll
            for (int j=0;j<17;j++){
                bfx8 b = *(const bfx8*)&Wk[(size_t)(j*16 + rl)*KP_ + kg];
                acc[j] = __builtin_amdgcn_mfma_f32_16x16x32_bf16(a, b, acc[j], 0,0,0);
            }
        }
        __syncthreads();
    }
#pragma unroll
    for (int j=0;j<17;j++){
        int n = j*16 + rl;
        if (n < OUT_){
            float sl = slope[n];
#pragma unroll
            for (int r=0;r<4;r++){
                int mrow = m0 + wave*16 + quad*4 + r;
                outp[(size_t)mrow*OUT_ + n] = 1.2f * sigf(sl*acc[j][r]);
            }
        }
    }
}

extern "C" void kernel_launch(void* const* d_in, const int* in_sizes, int n_in,
                              void* d_out, int out_size, void* d_ws, size_t ws_size,
                              hipStream_t stream) {
    const float* x      = (const float*)d_in[0];
    const float* Wih_f  = (const float*)d_in[1];
    const float* Whh_f  = (const float*)d_in[2];
    const float* bih_f  = (const float*)d_in[3];
    const float* bhh_f  = (const float*)d_in[4];
    const float* Wih_b  = (const float*)d_in[5];
    const float* Whh_b  = (const float*)d_in[6];
    const float* bih_b  = (const float*)d_in[7];
    const float* bhh_b  = (const float*)d_in[8];
    const float* base_w = (const float*)d_in[9];
    const float* spl_w  = (const float*)d_in[10];
    const float* spl_s  = (const float*)d_in[11];
    const float* slope  = (const float*)d_in[12];

    char* ws = (char*)d_ws;
    __hip_bfloat16* gi0 = (__hip_bfloat16*)ws;
    __hip_bfloat16* gi1 = (__hip_bfloat16*)(ws + OFF_GI1);
    float*          ft  = (float*)(ws + OFF_FEAT);
    __hip_bfloat16* Wk  = (__hip_bfloat16*)(ws + OFF_WK);
    __hip_bfloat16* Wb  = (__hip_bfloat16*)(ws + OFF_WB);
    float* outp = (float*)d_out;

    hipLaunchKernelGGL(kprep, dim3((NP_*(KP_/8) + 255)/256), dim3(256), 0, stream,
                       base_w, spl_w, spl_s, Wk);
    hipLaunchKernelGGL(wprep, dim3((NGI_*(KP1_/8) + 255)/256), dim3(256), 0, stream,
                       Wih_f, Wih_b, Wb);
    hipLaunchKernelGGL(k1_gemm, dim3(3, 500), dim3(256), 0, stream,
                       x, Wb, bih_f, bih_b, gi0, gi1);
    hipLaunchKernelGGL(k2_gru, dim3(2000), dim3(64), 0, stream,
                       gi0, gi1, Whh_f, bhh_f, Whh_b, bhh_b, ft);
    hipLaunchKernelGGL(k3_kan, dim3(1000), dim3(256), 0, stream,
                       ft, Wk, slope, outp);
}